// Round 10
// baseline (2305.465 us; speedup 1.0000x reference)
//
#include <hip/hip_runtime.h>
#include <stdint.h>

// Echo-state network (fp32 in, fp32 out). Round 24: fatter waves on the R23
// skeleton. R23 (global_load_lds dbuf staging, 1 barrier/chunk) = 1511 us,
// LDS-read-port-bound: 16x32 wave tiles make all 4 waves read IDENTICAL B
// fragments (x4 redundancy, B = 2/3 of read traffic). Fix: block = 128 thr
// (2 waves), block tile 64x64, wave tile 32x64 (2m x 4nf 16x16x32 frags):
// port cycles per output ~0.54x. Grid 384 (XCD-swizzled), LDS 64 KB/block ->
// 2 blocks/CU. Staging: same GLOAD16 DMA + XOR swizzle on both sides (rule
// #21), 16 instrs/wave/chunk (4 stripes x {Ahi,Alo,Bhi,Blo}). Per-output
// K-order, 3-MFMA hi/lo scheme, shuffle trees and head grouping
// (g = b*32 + it*2 + cg) identical to R18/R21/R23 -> bit-identical numerics.
// amdgpu_waves_per_eu(1,2): LDS caps occupancy at 2 blocks/CU anyway; stop
// the backend from VGPR-squeezing the pipeline (R19 lesson).

typedef _Float16 f16;
typedef _Float16 f16x8 __attribute__((ext_vector_type(8)));
typedef float floatx4 __attribute__((ext_vector_type(4)));

#define N_TOT 256
#define T_TOT 70
#define V_TOT 64
#define B_TOT 6
#define H_TOT 1024
#define C_TOT 4
#define F_TOT (B_TOT * H_TOT)
#define G_TOT 192       // partial groups = 6 * 32-col groups (unchanged)
#define LO_SCALE 4096.0f
#define LO_INV   (1.0f / 4096.0f)

union H8 { f16 h[8]; uint4 v; };

// global->LDS DMA, 16 B per lane. LDS dest = wave-uniform base + lane*16.
#define GLOAD16(g, l)                                                        \
    __builtin_amdgcn_global_load_lds(                                        \
        (const __attribute__((address_space(1))) void*)(g),                  \
        (__attribute__((address_space(3))) void*)(l), 16, 0, 0)

// ---------------------------------------------------------------------------
// One-time fp32 -> (hi, lo*4096) f16 split, 8 elems/thread. n % 2048 == 0.
// ---------------------------------------------------------------------------
__global__ __launch_bounds__(256)
void split_f32(const float* __restrict__ src, f16* __restrict__ hi,
               f16* __restrict__ lo, int n)
{
    const int i = (blockIdx.x * 256 + threadIdx.x) * 8;
    if (i + 8 > n) return;
    const float4 a = *(const float4*)&src[i];
    const float4 b = *(const float4*)&src[i + 4];
    const float x[8] = {a.x, a.y, a.z, a.w, b.x, b.y, b.z, b.w};
    H8 H, L;
#pragma unroll
    for (int j = 0; j < 8; ++j) {
        const f16 h = (f16)x[j];
        H.h[j] = h;
        L.h[j] = (f16)((x[j] - (float)h) * LO_SCALE);
    }
    *(uint4*)&hi[i] = H.v;
    *(uint4*)&lo[i] = L.v;
}

// ---------------------------------------------------------------------------
// Final head reduce + argmax. Block = t (70), thread = n (256).
// ---------------------------------------------------------------------------
__global__ __launch_bounds__(256)
void head_reduce(const float* __restrict__ part,
                 const float* __restrict__ b_lin,
                 float* __restrict__ logits,
                 float* __restrict__ preds)
{
    const int t = blockIdx.x;
    const int n = threadIdx.x;

    float a0 = b_lin[t * C_TOT + 0];
    float a1 = b_lin[t * C_TOT + 1];
    float a2 = b_lin[t * C_TOT + 2];
    float a3 = b_lin[t * C_TOT + 3];

    const float* p = part + (((size_t)t * G_TOT) * N_TOT + n) * C_TOT;
    for (int g = 0; g < G_TOT; ++g) {
        const float4 v = *(const float4*)&p[(size_t)g * N_TOT * C_TOT];
        a0 += v.x; a1 += v.y; a2 += v.z; a3 += v.w;
    }

    float4 o = {a0, a1, a2, a3};
    *(float4*)&logits[((size_t)t * N_TOT + n) * C_TOT] = o;

    int arg = 0;
    float best = a0;
    if (a1 > best) { best = a1; arg = 1; }
    if (a2 > best) { best = a2; arg = 2; }
    if (a3 > best) { best = a3; arg = 3; }
    preds[(size_t)t * N_TOT + n] = (float)arg;
}

// ---------------------------------------------------------------------------
// Fused step+head: S_new = tanh(S W_res^T + X_t W_in^T); partials -> part[].
// Tile 64(M) x 64(I); grid = 6*16*4 = 384 (XCD-swizzled); block = 128 thr =
// 2 waves (wave = 32-row half, 2m x 4nf 16x16x32 frags). 17 chunks of K=64
// (16 W_res + 1 W_in/X). Staging: global_load_lds into 2-deep LDS dbuf,
// XOR-swizzled both sides, 1 barrier/chunk.
// ---------------------------------------------------------------------------
__global__ __launch_bounds__(128)
__attribute__((amdgpu_waves_per_eu(1, 2)))
void esn_step_fused(const f16* __restrict__ Xhi,   const f16* __restrict__ Xlo,
                    const f16* __restrict__ Whi,   const f16* __restrict__ Wlo,
                    const f16* __restrict__ Wihi,  const f16* __restrict__ Wilo,
                    const f16* __restrict__ shi_p, const f16* __restrict__ slo_p,
                    f16* __restrict__ shi_n,       f16* __restrict__ slo_n,
                    const float* __restrict__ W_lin, float* __restrict__ part,
                    int t, int first)
{
    __shared__ f16 As_hi[2][64 * 64];
    __shared__ f16 As_lo[2][64 * 64];
    __shared__ f16 Bs_hi[2][64 * 64];
    __shared__ f16 Bs_lo[2][64 * 64];

    // XCD-aware bijective swizzle (384 % 8 == 0), (b,it,mt)-major.
    const int p   = blockIdx.x;
    const int l   = (p & 7) * 48 + (p >> 3);
    const int mt  = l & 3;           // batch tile 0..3  (64 rows)
    const int bi  = l >> 2;          // 0..95
    const int b   = bi >> 4;         // reservoir block 0..5
    const int it  = bi & 15;         // unit tile 0..15  (64 cols)

    const int tid  = threadIdx.x;
    const int w    = tid >> 6;       // wave = M-half (0..1)
    const int lane = tid & 63;
    const int l16  = lane & 15;
    const int oct  = lane >> 4;
    const int r8   = lane >> 3;      // stripe row 0..7
    const int sw   = ((lane & 7) ^ r8) << 3;   // swizzled source col (f16)

    // per-lane global source pointers (16B-aligned)
    const f16* Ah  = shi_p + (size_t)(b * N_TOT + mt * 64 + w * 32 + r8) * H_TOT + sw;
    const f16* Al  = slo_p + (size_t)(b * N_TOT + mt * 64 + w * 32 + r8) * H_TOT + sw;
    const f16* Bh  = Whi   + (size_t)(b * H_TOT + it * 64 + w * 32 + r8) * H_TOT + sw;
    const f16* Bl  = Wlo   + (size_t)(b * H_TOT + it * 64 + w * 32 + r8) * H_TOT + sw;
    const f16* Xh  = Xhi + ((size_t)(mt * 64 + w * 32 + r8) * T_TOT + t) * V_TOT + sw;
    const f16* Xl  = Xlo + ((size_t)(mt * 64 + w * 32 + r8) * T_TOT + t) * V_TOT + sw;
    const f16* Wih = Wihi + (size_t)(b * H_TOT + it * 64 + w * 32 + r8) * V_TOT + sw;
    const f16* Wil = Wilo + (size_t)(b * H_TOT + it * 64 + w * 32 + r8) * V_TOT + sw;

    // stage chunk k into buffer k&1 (k==16 -> input term X / W_in).
    // Wave w stages rows [w*32, w*32+32) of both A and B tiles (4 stripes).
    auto STAGE = [&](int k) {
        const int bb = k & 1;
        if (k < 16) {
            const size_t off = (size_t)k * 64;
#pragma unroll
            for (int s = 0; s < 4; ++s) {
                const int d = (w * 32 + s * 8) * 64;
                GLOAD16(Ah + (size_t)s * 8 * H_TOT + off, &As_hi[bb][d]);
                GLOAD16(Al + (size_t)s * 8 * H_TOT + off, &As_lo[bb][d]);
                GLOAD16(Bh + (size_t)s * 8 * H_TOT + off, &Bs_hi[bb][d]);
                GLOAD16(Bl + (size_t)s * 8 * H_TOT + off, &Bs_lo[bb][d]);
            }
        } else {
#pragma unroll
            for (int s = 0; s < 4; ++s) {
                const int d = (w * 32 + s * 8) * 64;
                GLOAD16(Xh  + (size_t)s * 8 * T_TOT * V_TOT, &As_hi[bb][d]);
                GLOAD16(Xl  + (size_t)s * 8 * T_TOT * V_TOT, &As_lo[bb][d]);
                GLOAD16(Wih + (size_t)s * 8 * V_TOT,         &Bs_hi[bb][d]);
                GLOAD16(Wil + (size_t)s * 8 * V_TOT,         &Bs_lo[bb][d]);
            }
        }
    };

    floatx4 acc[2][4], accl[2][4];
#pragma unroll
    for (int m = 0; m < 2; ++m)
#pragma unroll
        for (int nf = 0; nf < 4; ++nf) {
            acc[m][nf] = (floatx4)(0.0f);
            accl[m][nf] = (floatx4)(0.0f);
        }

    // swizzled ds_read address components (f16 elems)
    const int xsw = (l16 & 7) << 3;
    const int arow_lds[2] = { (w * 32 + l16) * 64, (w * 32 + 16 + l16) * 64 };
    const int brow_lds[4] = { l16 * 64, (16 + l16) * 64,
                              (32 + l16) * 64, (48 + l16) * 64 };
    const int colk[2] = { (0 + oct * 8) ^ xsw, (32 + oct * 8) ^ xsw };

    const int kc0 = first ? 16 : 0;
    STAGE(kc0);
    __syncthreads();   // vmcnt(0) drain: buffer kc0&1 ready

    for (int kc = kc0; kc <= 16; ++kc) {
        const int bb = kc & 1;
        if (kc < 16) STAGE(kc + 1);   // DMA next chunk into other buffer

#pragma unroll
        for (int half = 0; half < 2; ++half) {
            f16x8 ah[2], al[2];
#pragma unroll
            for (int m = 0; m < 2; ++m) {
                ah[m] = *(const f16x8*)&As_hi[bb][arow_lds[m] + colk[half]];
                al[m] = *(const f16x8*)&As_lo[bb][arow_lds[m] + colk[half]];
            }
#pragma unroll
            for (int nf = 0; nf < 4; ++nf) {
                const f16x8 bh = *(const f16x8*)&Bs_hi[bb][brow_lds[nf] + colk[half]];
                const f16x8 bl = *(const f16x8*)&Bs_lo[bb][brow_lds[nf] + colk[half]];
#pragma unroll
                for (int m = 0; m < 2; ++m) {
                    acc[m][nf]  = __builtin_amdgcn_mfma_f32_16x16x32_f16(ah[m], bh, acc[m][nf], 0, 0, 0);
                    accl[m][nf] = __builtin_amdgcn_mfma_f32_16x16x32_f16(ah[m], bl, accl[m][nf], 0, 0, 0);
                    accl[m][nf] = __builtin_amdgcn_mfma_f32_16x16x32_f16(al[m], bh, accl[m][nf], 0, 0, 0);
                }
            }
        }
        if (kc < 16) __syncthreads();   // next buffer DMA'd; this buffer free
    }

    // ---- epilogue: tanh -> split-store state; head partial -> part[] ----
    // C/D map (16x16x32): col = lane&15, row = oct*4 + r.
    const int nbase = mt * 64;
    const int ibase = it * 64;

    const float* wl = W_lin + (size_t)t * C_TOT * F_TOT + b * H_TOT + ibase;
    float wv[4][4];
#pragma unroll
    for (int c = 0; c < 4; ++c)
#pragma unroll
        for (int nf = 0; nf < 4; ++nf)
            wv[c][nf] = wl[(size_t)c * F_TOT + nf * 16 + l16];

    float sval[2][4][4];   // [m][nf][r]
#pragma unroll
    for (int m = 0; m < 2; ++m)
#pragma unroll
        for (int nf = 0; nf < 4; ++nf)
#pragma unroll
            for (int r = 0; r < 4; ++r) {
                const int mrow = w * 32 + m * 16 + oct * 4 + r; // batch row in tile
                const int ii   = nf * 16 + l16;                 // unit col in tile
                const float s = tanhf(acc[m][nf][r] + accl[m][nf][r] * LO_INV);
                sval[m][nf][r] = s;
                const f16 h = (f16)s;
                const size_t oidx = (size_t)(b * N_TOT + nbase + mrow) * H_TOT + ibase + ii;
                shi_n[oidx] = h;
                slo_n[oidx] = (f16)((s - (float)h) * LO_SCALE);
            }

    // head partials: two 32-col groups per wave (cg = nf pair), same grouping
    // and pairwise+tree order as R18/R21 -> bit-identical.
#pragma unroll
    for (int cg = 0; cg < 2; ++cg) {
        const int g = b * 32 + it * 2 + cg;
#pragma unroll
        for (int m = 0; m < 2; ++m)
#pragma unroll
            for (int r = 0; r < 4; ++r) {
                float v[4];
#pragma unroll
                for (int c = 0; c < 4; ++c) {
                    float x = sval[m][2 * cg][r] * wv[c][2 * cg]
                            + sval[m][2 * cg + 1][r] * wv[c][2 * cg + 1];
                    x += __shfl_xor(x, 1);
                    x += __shfl_xor(x, 2);
                    x += __shfl_xor(x, 4);
                    x += __shfl_xor(x, 8);
                    v[c] = x;
                }
                if (l16 == 0) {
                    const int n = nbase + w * 32 + m * 16 + oct * 4 + r;
                    float4 o = {v[0], v[1], v[2], v[3]};
                    *(float4*)&part[(((size_t)t * G_TOT + g) * N_TOT + n) * C_TOT] = o;
                }
            }
    }
}

extern "C" void kernel_launch(void* const* d_in, const int* in_sizes, int n_in,
                              void* d_out, int out_size, void* d_ws, size_t ws_size,
                              hipStream_t stream) {
    const float* X     = (const float*)d_in[0]; // [256,70,64]
    const float* W_res = (const float*)d_in[1]; // [6,1024,1024]
    const float* W_in  = (const float*)d_in[2]; // [6,1024,64]
    const float* W_lin = (const float*)d_in[3]; // [70,4,6144]
    const float* b_lin = (const float*)d_in[4]; // [70,4]

    float* out    = (float*)d_out;
    float* logits = out;                                  // T*N*C fp32
    float* preds  = out + (size_t)T_TOT * N_TOT * C_TOT;  // T*N   fp32

    const size_t nWres = (size_t)B_TOT * H_TOT * H_TOT;   // 6,291,456
    const size_t nWin  = (size_t)B_TOT * H_TOT * V_TOT;   //   393,216
    const size_t nX    = (size_t)N_TOT * T_TOT * V_TOT;   // 1,146,880
    const size_t nS    = (size_t)B_TOT * N_TOT * H_TOT;   // 1,572,864

    f16* p    = (f16*)d_ws;                               // f16 arena ~43.9 MB
    f16* Whi  = p;  p += nWres;
    f16* Wlo  = p;  p += nWres;
    f16* Wihi = p;  p += nWin;
    f16* Wilo = p;  p += nWin;
    f16* Xhi  = p;  p += nX;
    f16* Xlo  = p;  p += nX;
    f16* sAh  = p;  p += nS;
    f16* sAl  = p;  p += nS;
    f16* sBh  = p;  p += nS;
    f16* sBl  = p;  p += nS;
    float* part = (float*)p;                              // +55 MB (ws ~268 MB)

    // one-time pre-splits (stream-ordered before the loop)
    split_f32<<<(int)(nWres / 2048), 256, 0, stream>>>(W_res, Whi, Wlo, (int)nWres);
    split_f32<<<(int)(nWin  / 2048), 256, 0, stream>>>(W_in, Wihi, Wilo, (int)nWin);
    split_f32<<<(int)(nX    / 2048), 256, 0, stream>>>(X, Xhi, Xlo, (int)nX);

    for (int t = 0; t < T_TOT; ++t) {
        const f16 *ph, *pl;
        f16 *nh, *nl;
        if (t & 1) { ph = sBh; pl = sBl; nh = sAh; nl = sAl; }
        else       { ph = sAh; pl = sAl; nh = sBh; nl = sBl; }
        esn_step_fused<<<B_TOT * 16 * 4, 128, 0, stream>>>(
            Xhi, Xlo, Whi, Wlo, Wihi, Wilo, ph, pl, nh, nl,
            W_lin, part, t, t == 0 ? 1 : 0);
    }
    head_reduce<<<T_TOT, 256, 0, stream>>>(part, b_lin, logits, preds);
}

// Round 11
// 1883.478 us; speedup vs baseline: 1.2240x; 1.2240x over previous
//
#include <hip/hip_runtime.h>
#include <stdint.h>

// Echo-state network (fp32 in, fp32 out). Round 25: 4-deep DMA pipeline with
// counted vmcnt barriers on the R23 skeleton (1511 us).
// R23 residual: per-chunk __syncthreads drains vmcnt(0), i.e. waits on the
// STAGE(kc+1) DMAs issued only ~260 cy earlier -> ~700 cy latency stall per
// chunk (17x/step ~= 5 us, matches model-vs-measured gap). R24 lesson: fixes
// must keep >=12 waves/CU and grid 768. This round: BK=32 (34 chunks),
// 4-deep LDS buffers (4 x 12 KB = 48 KB, same footprint/occupancy as R23),
// STAGE(kc+3) issued during chunk kc, barrier = {sched_barrier; s_waitcnt
// vmcnt(6) lgkmcnt(0); s_barrier; sched_barrier} -> waits only STAGE(kc+1)
// (issued 2 chunks earlier, latency fully hidden); newest 6 DMAs ride across.
// STAGE = exactly 3 uniform GLOAD16s: W_res/W_in repacked by csplit32 into
// hi|lo-combined 32-K panels [row][kc][hi32|lo32] (B = 1 GLOAD); A (state/X)
// stays split hi/lo (2 GLOADs). XOR swizzles on BOTH sides (rule #21):
// A granule cg^((r>>1)&3) (2-way free), B granule cg^(r&7) (2-way free).
// K-order ascending 32-windows = identical accumulation -> bit-identical.
// Tail peeled with vmcnt 6 -> 3 -> 0. Epilogue/head/head_reduce verbatim R23.

typedef _Float16 f16;
typedef _Float16 f16x8 __attribute__((ext_vector_type(8)));
typedef float floatx4 __attribute__((ext_vector_type(4)));

#define N_TOT 256
#define T_TOT 70
#define V_TOT 64
#define B_TOT 6
#define H_TOT 1024
#define C_TOT 4
#define F_TOT (B_TOT * H_TOT)
#define G_TOT 192       // partial groups = B_TOT * 32 unit-tiles
#define LO_SCALE 4096.0f
#define LO_INV   (1.0f / 4096.0f)

union H8 { f16 h[8]; uint4 v; };

// global->LDS DMA, 16 B per lane. LDS dest = wave-uniform base + lane*16.
#define GLOAD16(g, l)                                                        \
    __builtin_amdgcn_global_load_lds(                                        \
        (const __attribute__((address_space(1))) void*)(g),                  \
        (__attribute__((address_space(3))) void*)(l), 16, 0, 0)

// Counted-wait barrier: newest N vmem ops (in-flight DMAs) ride across.
#define LDSBAR(N)                                                            \
    do {                                                                     \
        __builtin_amdgcn_sched_barrier(0);                                   \
        asm volatile("s_waitcnt vmcnt(" #N ") lgkmcnt(0)" ::: "memory");     \
        __builtin_amdgcn_s_barrier();                                        \
        __builtin_amdgcn_sched_barrier(0);                                   \
    } while (0)

// ---------------------------------------------------------------------------
// One-time fp32 -> (hi, lo*4096) f16 split (X only), 8 elems/thread.
// ---------------------------------------------------------------------------
__global__ __launch_bounds__(256)
void split_f32(const float* __restrict__ src, f16* __restrict__ hi,
               f16* __restrict__ lo, int n)
{
    const int i = (blockIdx.x * 256 + threadIdx.x) * 8;
    if (i + 8 > n) return;
    const float4 a = *(const float4*)&src[i];
    const float4 b = *(const float4*)&src[i + 4];
    const float x[8] = {a.x, a.y, a.z, a.w, b.x, b.y, b.z, b.w};
    H8 H, L;
#pragma unroll
    for (int j = 0; j < 8; ++j) {
        const f16 h = (f16)x[j];
        H.h[j] = h;
        L.h[j] = (f16)((x[j] - (float)h) * LO_SCALE);
    }
    *(uint4*)&hi[i] = H.v;
    *(uint4*)&lo[i] = L.v;
}

// ---------------------------------------------------------------------------
// One-time fp32 -> hi|lo-combined 32-K panels: dst[row][k>>5][ (k&31) ] = hi,
// dst[row][k>>5][32 + (k&31)] = lo*4096. K % 32 == 0.
// ---------------------------------------------------------------------------
__global__ __launch_bounds__(256)
void csplit32(const float* __restrict__ src, f16* __restrict__ dst,
              int n, int K)
{
    const int i = (blockIdx.x * 256 + threadIdx.x) * 8;
    if (i + 8 > n) return;
    const float4 a = *(const float4*)&src[i];
    const float4 b = *(const float4*)&src[i + 4];
    const float x[8] = {a.x, a.y, a.z, a.w, b.x, b.y, b.z, b.w};
    H8 H, L;
#pragma unroll
    for (int j = 0; j < 8; ++j) {
        const f16 h = (f16)x[j];
        H.h[j] = h;
        L.h[j] = (f16)((x[j] - (float)h) * LO_SCALE);
    }
    const int row = i / K;
    const int k   = i - row * K;
    const size_t o = ((size_t)row * (K >> 5) + (k >> 5)) * 64 + (k & 31);
    *(uint4*)&dst[o]      = H.v;
    *(uint4*)&dst[o + 32] = L.v;
}

// ---------------------------------------------------------------------------
// Final head reduce + argmax. Block = t (70), thread = n (256).
// ---------------------------------------------------------------------------
__global__ __launch_bounds__(256)
void head_reduce(const float* __restrict__ part,
                 const float* __restrict__ b_lin,
                 float* __restrict__ logits,
                 float* __restrict__ preds)
{
    const int t = blockIdx.x;
    const int n = threadIdx.x;

    float a0 = b_lin[t * C_TOT + 0];
    float a1 = b_lin[t * C_TOT + 1];
    float a2 = b_lin[t * C_TOT + 2];
    float a3 = b_lin[t * C_TOT + 3];

    const float* p = part + (((size_t)t * G_TOT) * N_TOT + n) * C_TOT;
    for (int g = 0; g < G_TOT; ++g) {
        const float4 v = *(const float4*)&p[(size_t)g * N_TOT * C_TOT];
        a0 += v.x; a1 += v.y; a2 += v.z; a3 += v.w;
    }

    float4 o = {a0, a1, a2, a3};
    *(float4*)&logits[((size_t)t * N_TOT + n) * C_TOT] = o;

    int arg = 0;
    float best = a0;
    if (a1 > best) { best = a1; arg = 1; }
    if (a2 > best) { best = a2; arg = 2; }
    if (a3 > best) { best = a3; arg = 3; }
    preds[(size_t)t * N_TOT + n] = (float)arg;
}

// ---------------------------------------------------------------------------
// Fused step+head: S_new = tanh(S W_res^T + X_t W_in^T); partials -> part[].
// Tile 64(M) x 32(I); grid = 768 (XCD-swizzled); 4 waves = M-quadrants.
// 34 chunks of K=32 (32 W_res + 2 input). 4-deep LDS DMA pipeline, counted
// vmcnt barriers (6 -> 3 -> 0 at tail), 1 barrier/chunk.
// ---------------------------------------------------------------------------
__global__ __launch_bounds__(256)
void esn_step_fused(const f16* __restrict__ Xhi,   const f16* __restrict__ Xlo,
                    const f16* __restrict__ Wc,    const f16* __restrict__ Wic,
                    const f16* __restrict__ shi_p, const f16* __restrict__ slo_p,
                    f16* __restrict__ shi_n,       f16* __restrict__ slo_n,
                    const float* __restrict__ W_lin, float* __restrict__ part,
                    int t, int first)
{
    __shared__ f16 As_hi[4][64 * 32];   // 4 bufs x 4 KB
    __shared__ f16 As_lo[4][64 * 32];   // 4 bufs x 4 KB
    __shared__ f16 Bs[4][32 * 64];      // 4 bufs x 4 KB (hi|lo combined)

    // XCD-aware bijective swizzle (768 % 8 == 0), (b,it,mt)-major.
    const int p   = blockIdx.x;
    const int l   = (p & 7) * 96 + (p >> 3);
    const int mt  = l & 3;           // batch tile 0..3  (64 rows)
    const int bi  = l >> 2;          // 0..191
    const int b   = bi >> 5;         // reservoir block 0..5
    const int it  = bi & 31;         // unit tile 0..31  (32 cols)

    const int tid  = threadIdx.x;
    const int w    = tid >> 6;       // wave = M-quadrant
    const int lane = tid & 63;
    const int l16  = lane & 15;
    const int oct  = lane >> 4;

    // ---- staging source maps (per-lane, pre-swizzled; 16B-aligned) ----
    // A tile [64 rows][32 cols]: thread -> (row = tid>>2, cg = tid&3);
    // source granule = cg ^ ((row>>1)&3)  (bank-free read swizzle).
    const int arow = tid >> 2;
    const int acg  = ((tid & 3) ^ ((tid >> 3) & 3)) << 3;   // f16 col offset
    // B tile [32 rows][64 cols hi|lo]: thread -> (row = tid>>3, cg = tid&7);
    // source granule = cg ^ (row&7).
    const int brow = tid >> 3;
    const int bcg  = ((tid & 7) ^ ((tid >> 3) & 7)) << 3;   // f16 col offset

    const f16* Asrc_h = shi_p + (size_t)(b * N_TOT + mt * 64 + arow) * H_TOT + acg;
    const f16* Asrc_l = slo_p + (size_t)(b * N_TOT + mt * 64 + arow) * H_TOT + acg;
    const f16* Bsrc   = Wc  + ((size_t)(b * H_TOT + it * 32 + brow) * 32) * 64 + bcg;
    const f16* Xsrc_h = Xhi + ((size_t)(mt * 64 + arow) * T_TOT + t) * V_TOT + acg;
    const f16* Xsrc_l = Xlo + ((size_t)(mt * 64 + arow) * T_TOT + t) * V_TOT + acg;
    const f16* Wisrc  = Wic + ((size_t)(b * H_TOT + it * 32 + brow) * 2) * 64 + bcg;

    // LDS dests: all three tiles are lane-linear; wave base = w*512 f16.
    const int dst = w * 512;

    // stage chunk k into buffer k&3 (k in [0,32) = W_res; 32/33 = input)
    auto STAGE = [&](int k) {
        const int bb = k & 3;
        if (k < 32) {
            GLOAD16(Asrc_h + k * 32, &As_hi[bb][dst]);
            GLOAD16(Asrc_l + k * 32, &As_lo[bb][dst]);
            GLOAD16(Bsrc + k * 64,   &Bs[bb][dst]);
        } else {
            const int kc2 = k - 32;
            GLOAD16(Xsrc_h + kc2 * 32, &As_hi[bb][dst]);
            GLOAD16(Xsrc_l + kc2 * 32, &As_lo[bb][dst]);
            GLOAD16(Wisrc + kc2 * 64,  &Bs[bb][dst]);
        }
    };

    floatx4 acc[2], accl[2];
#pragma unroll
    for (int j = 0; j < 2; ++j) { acc[j] = (floatx4)(0.0f); accl[j] = (floatx4)(0.0f); }

    // ---- swizzled ds_read addresses (f16 elems), chunk-invariant ----
    const int aoff = (w * 16 + l16) * 32 + ((oct ^ ((l16 >> 1) & 3)) << 3);
    const int bx   = (l16 & 7) << 3;
    int bhoff[2], bloff[2];
#pragma unroll
    for (int nf = 0; nf < 2; ++nf) {
        bhoff[nf] = (nf * 16 + l16) * 64 + ((oct * 8) ^ bx);
        bloff[nf] = (nf * 16 + l16) * 64 + ((32 + oct * 8) ^ bx);
    }

    auto COMPUTE = [&](int bb) {
        const f16x8 ah = *(const f16x8*)&As_hi[bb][aoff];
        const f16x8 al = *(const f16x8*)&As_lo[bb][aoff];
#pragma unroll
        for (int nf = 0; nf < 2; ++nf) {
            const f16x8 bh = *(const f16x8*)&Bs[bb][bhoff[nf]];
            const f16x8 bl = *(const f16x8*)&Bs[bb][bloff[nf]];
            acc[nf]  = __builtin_amdgcn_mfma_f32_16x16x32_f16(ah, bh, acc[nf], 0, 0, 0);
            accl[nf] = __builtin_amdgcn_mfma_f32_16x16x32_f16(ah, bl, accl[nf], 0, 0, 0);
            accl[nf] = __builtin_amdgcn_mfma_f32_16x16x32_f16(al, bh, accl[nf], 0, 0, 0);
        }
    };

    if (!first) {
        STAGE(0); STAGE(1); STAGE(2);
        LDSBAR(6);                       // chunk-0 DMAs done; 1,2 in flight
        for (int kc = 0; kc < 31; ++kc) {
            STAGE(kc + 3);               // 3 DMAs into buf (kc+3)&3
            COMPUTE(kc & 3);
            LDSBAR(6);                   // STAGE(kc+1) done; newest 6 ride
        }
        COMPUTE(31 & 3); LDSBAR(3);      // STAGE(32) done
        COMPUTE(32 & 3); LDSBAR(0);      // STAGE(33) done
        COMPUTE(33 & 3);
    } else {
        // t == 0: state is zero; only the two input chunks (bufs 0,1).
        STAGE(32); STAGE(33);
        LDSBAR(3);
        COMPUTE(32 & 3); LDSBAR(0);
        COMPUTE(33 & 3);
    }

    // ---- epilogue: tanh -> split-store state; head partial -> part[] ----
    // C/D map (16x16x32): col = lane&15, row = oct*4 + r.
    const int nbase = mt * 64;
    const int ibase = it * 32;

    const float* wl = W_lin + (size_t)t * C_TOT * F_TOT + b * H_TOT + ibase;
    float wv[4][2];
#pragma unroll
    for (int c = 0; c < 4; ++c)
#pragma unroll
        for (int nf = 0; nf < 2; ++nf)
            wv[c][nf] = wl[(size_t)c * F_TOT + nf * 16 + l16];

    float sval[2][4];
#pragma unroll
    for (int nf = 0; nf < 2; ++nf)
#pragma unroll
        for (int r = 0; r < 4; ++r) {
            const int m  = w * 16 + oct * 4 + r;    // batch row within tile
            const int ii = nf * 16 + l16;           // unit col within tile
            const float s = tanhf(acc[nf][r] + accl[nf][r] * LO_INV);
            sval[nf][r] = s;
            const f16 h = (f16)s;
            const size_t oidx = (size_t)(b * N_TOT + nbase + m) * H_TOT + ibase + ii;
            shi_n[oidx] = h;
            slo_n[oidx] = (f16)((s - (float)h) * LO_SCALE);
        }

    const int g = b * 32 + it;
#pragma unroll
    for (int r = 0; r < 4; ++r) {
        float v[4];
#pragma unroll
        for (int c = 0; c < 4; ++c) {
            float x = sval[0][r] * wv[c][0] + sval[1][r] * wv[c][1];
            x += __shfl_xor(x, 1);
            x += __shfl_xor(x, 2);
            x += __shfl_xor(x, 4);
            x += __shfl_xor(x, 8);
            v[c] = x;
        }
        if (l16 == 0) {
            const int n = nbase + w * 16 + oct * 4 + r;
            float4 o = {v[0], v[1], v[2], v[3]};
            *(float4*)&part[(((size_t)t * G_TOT + g) * N_TOT + n) * C_TOT] = o;
        }
    }
}

extern "C" void kernel_launch(void* const* d_in, const int* in_sizes, int n_in,
                              void* d_out, int out_size, void* d_ws, size_t ws_size,
                              hipStream_t stream) {
    const float* X     = (const float*)d_in[0]; // [256,70,64]
    const float* W_res = (const float*)d_in[1]; // [6,1024,1024]
    const float* W_in  = (const float*)d_in[2]; // [6,1024,64]
    const float* W_lin = (const float*)d_in[3]; // [70,4,6144]
    const float* b_lin = (const float*)d_in[4]; // [70,4]

    float* out    = (float*)d_out;
    float* logits = out;                                  // T*N*C fp32
    float* preds  = out + (size_t)T_TOT * N_TOT * C_TOT;  // T*N   fp32

    const size_t nWres = (size_t)B_TOT * H_TOT * H_TOT;   // 6,291,456
    const size_t nWin  = (size_t)B_TOT * H_TOT * V_TOT;   //   393,216
    const size_t nX    = (size_t)N_TOT * T_TOT * V_TOT;   // 1,146,880
    const size_t nS    = (size_t)B_TOT * N_TOT * H_TOT;   // 1,572,864

    f16* p    = (f16*)d_ws;                               // f16 arena ~43.9 MB
    f16* Wc   = p;  p += nWres * 2;   // combined hi|lo panels
    f16* Wic  = p;  p += nWin * 2;
    f16* Xhi  = p;  p += nX;
    f16* Xlo  = p;  p += nX;
    f16* sAh  = p;  p += nS;
    f16* sAl  = p;  p += nS;
    f16* sBh  = p;  p += nS;
    f16* sBl  = p;  p += nS;
    float* part = (float*)p;                              // +55 MB (ws ~268 MB)

    // one-time pre-splits (stream-ordered before the loop)
    csplit32<<<(int)(nWres / 2048), 256, 0, stream>>>(W_res, Wc, (int)nWres, H_TOT);
    csplit32<<<(int)(nWin  / 2048), 256, 0, stream>>>(W_in, Wic, (int)nWin, V_TOT);
    split_f32<<<(int)(nX   / 2048), 256, 0, stream>>>(X, Xhi, Xlo, (int)nX);

    for (int t = 0; t < T_TOT; ++t) {
        const f16 *ph, *pl;
        f16 *nh, *nl;
        if (t & 1) { ph = sBh; pl = sBl; nh = sAh; nl = sAl; }
        else       { ph = sAh; pl = sAl; nh = sBh; nl = sBl; }
        esn_step_fused<<<B_TOT * 4 * 32, 256, 0, stream>>>(
            Xhi, Xlo, Wc, Wic, ph, pl, nh, nl,
            W_lin, part, t, t == 0 ? 1 : 0);
    }
    head_reduce<<<T_TOT, 256, 0, stream>>>(part, b_lin, logits, preds);
}

// Round 13
// 1548.557 us; speedup vs baseline: 1.4888x; 1.2163x over previous
//
#include <hip/hip_runtime.h>
#include <stdint.h>

// Echo-state network (fp32 in, fp32 out). Round 27: RESUBMIT of R26 (the
// bench container failed twice - infra flake; the kernel is a pure index
// remap of R23 which passed at 1511 us, with no new hang/fault surface).
// Theory: R23's per-phase stall is A-operand (state) DMAs crossing XCDs
// under the R18 swizzle -> L3 latency (~450-700 cy/phase). The 32 blocks
// (b,mt,it=0..31) form a CLOSED producer-consumer group: they produce
// exactly the state rows they consume next step. New decode pins each group
// to one XCD: xcd=p&7, s=p>>3, it=s&31, gid=xcd*3+(s>>5), b=gid>>2, mt=gid&3
// (bijective, 768=8x96). State slices (768 KB/XCD) stay L2-resident across
// steps -> A-DMAs become ~200cy L2 hits. STAGE issues B (possibly-L3) first.
// Work per tile unchanged -> bit-identical numerics. Everything else
// verbatim R23: GLOAD16 DMA staging, 2-deep dbuf, 1 __syncthreads/chunk,
// XOR swizzle both sides, 64x32 tile, hi/lo*4096 split, 3 MFMAs/product,
// fused head partials, head_reduce.

typedef _Float16 f16;
typedef _Float16 f16x8 __attribute__((ext_vector_type(8)));
typedef float floatx4 __attribute__((ext_vector_type(4)));

#define N_TOT 256
#define T_TOT 70
#define V_TOT 64
#define B_TOT 6
#define H_TOT 1024
#define C_TOT 4
#define F_TOT (B_TOT * H_TOT)
#define G_TOT 192       // partial groups = B_TOT * 32 unit-tiles
#define LO_SCALE 4096.0f
#define LO_INV   (1.0f / 4096.0f)

union H8 { f16 h[8]; uint4 v; };

// global->LDS DMA, 16 B per lane. LDS dest = wave-uniform base + lane*16.
#define GLOAD16(g, l)                                                        \
    __builtin_amdgcn_global_load_lds(                                        \
        (const __attribute__((address_space(1))) void*)(g),                  \
        (__attribute__((address_space(3))) void*)(l), 16, 0, 0)

// ---------------------------------------------------------------------------
// One-time fp32 -> (hi, lo*4096) f16 split, 8 elems/thread. n % 2048 == 0.
// ---------------------------------------------------------------------------
__global__ __launch_bounds__(256)
void split_f32(const float* __restrict__ src, f16* __restrict__ hi,
               f16* __restrict__ lo, int n)
{
    const int i = (blockIdx.x * 256 + threadIdx.x) * 8;
    if (i + 8 > n) return;
    const float4 a = *(const float4*)&src[i];
    const float4 b = *(const float4*)&src[i + 4];
    const float x[8] = {a.x, a.y, a.z, a.w, b.x, b.y, b.z, b.w};
    H8 H, L;
#pragma unroll
    for (int j = 0; j < 8; ++j) {
        const f16 h = (f16)x[j];
        H.h[j] = h;
        L.h[j] = (f16)((x[j] - (float)h) * LO_SCALE);
    }
    *(uint4*)&hi[i] = H.v;
    *(uint4*)&lo[i] = L.v;
}

// ---------------------------------------------------------------------------
// Final head reduce + argmax. Block = t (70), thread = n (256).
// ---------------------------------------------------------------------------
__global__ __launch_bounds__(256)
void head_reduce(const float* __restrict__ part,
                 const float* __restrict__ b_lin,
                 float* __restrict__ logits,
                 float* __restrict__ preds)
{
    const int t = blockIdx.x;
    const int n = threadIdx.x;

    float a0 = b_lin[t * C_TOT + 0];
    float a1 = b_lin[t * C_TOT + 1];
    float a2 = b_lin[t * C_TOT + 2];
    float a3 = b_lin[t * C_TOT + 3];

    const float* p = part + (((size_t)t * G_TOT) * N_TOT + n) * C_TOT;
    for (int g = 0; g < G_TOT; ++g) {
        const float4 v = *(const float4*)&p[(size_t)g * N_TOT * C_TOT];
        a0 += v.x; a1 += v.y; a2 += v.z; a3 += v.w;
    }

    float4 o = {a0, a1, a2, a3};
    *(float4*)&logits[((size_t)t * N_TOT + n) * C_TOT] = o;

    int arg = 0;
    float best = a0;
    if (a1 > best) { best = a1; arg = 1; }
    if (a2 > best) { best = a2; arg = 2; }
    if (a3 > best) { best = a3; arg = 3; }
    preds[(size_t)t * N_TOT + n] = (float)arg;
}

// ---------------------------------------------------------------------------
// Fused step+head: S_new = tanh(S W_res^T + X_t W_in^T); partials -> part[].
// Tile 64(M) x 32(I); grid = 768; 4 waves = M-quadrants, 1x2 16x16x32 f16
// fragments. 17 chunks of K=64 (16 W_res + 1 W_in/X). Staging: global_load_lds
// into 2-deep LDS dbuf, 1 barrier/chunk. Decode: closed-group XCD affinity.
// ---------------------------------------------------------------------------
__global__ __launch_bounds__(256)
void esn_step_fused(const f16* __restrict__ Xhi,   const f16* __restrict__ Xlo,
                    const f16* __restrict__ Whi,   const f16* __restrict__ Wlo,
                    const f16* __restrict__ Wihi,  const f16* __restrict__ Wilo,
                    const f16* __restrict__ shi_p, const f16* __restrict__ slo_p,
                    f16* __restrict__ shi_n,       f16* __restrict__ slo_n,
                    const float* __restrict__ W_lin, float* __restrict__ part,
                    int t, int first)
{
    __shared__ f16 As_hi[2][64 * 64];
    __shared__ f16 As_lo[2][64 * 64];
    __shared__ f16 Bs_hi[2][32 * 64];
    __shared__ f16 Bs_lo[2][32 * 64];

    // Producer-consumer closed-group XCD affinity (768 = 8 XCDs x 96):
    // XCD x owns (b,mt) groups {3x,3x+1,3x+2}; group (b,mt)'s 32 it-blocks
    // produce exactly the state rows they consume next step -> state stays
    // in this XCD's L2 across steps.
    const int p   = blockIdx.x;
    const int xcd = p & 7;
    const int s   = p >> 3;          // 0..95
    const int it  = s & 31;          // unit tile 0..31 (32 cols)
    const int gid = xcd * 3 + (s >> 5);  // 0..23
    const int b   = gid >> 2;        // reservoir block 0..5
    const int mt  = gid & 3;         // batch tile 0..3 (64 rows)

    const int tid  = threadIdx.x;
    const int w    = tid >> 6;       // wave = M-quadrant
    const int lane = tid & 63;
    const int l16  = lane & 15;
    const int oct  = lane >> 4;
    const int r8   = lane >> 3;      // stripe row 0..7
    const int sw   = ((lane & 7) ^ r8) << 3;   // swizzled source col (f16)

    // LDS stripe bases (f16 elems) - wave-uniform
    const int dA0 = (w * 16) * 64;
    const int dA1 = (w * 16 + 8) * 64;
    const int dB  = (w * 8) * 64;

    // per-lane global row indices
    const int arow0 = mt * 64 + w * 16 + r8;   // A rows, issue 0
    const int arow1 = arow0 + 8;               // A rows, issue 1
    const int brow  = it * 32 + w * 8 + r8;    // B rows

    // source base pointers (per-lane, 16B-aligned)
    const f16* Ah0 = shi_p + (size_t)(b * N_TOT + arow0) * H_TOT + sw;
    const f16* Ah1 = shi_p + (size_t)(b * N_TOT + arow1) * H_TOT + sw;
    const f16* Al0 = slo_p + (size_t)(b * N_TOT + arow0) * H_TOT + sw;
    const f16* Al1 = slo_p + (size_t)(b * N_TOT + arow1) * H_TOT + sw;
    const f16* Bh0 = Whi   + (size_t)(b * H_TOT + brow) * H_TOT + sw;
    const f16* Bl0 = Wlo   + (size_t)(b * H_TOT + brow) * H_TOT + sw;
    const f16* Xh0 = Xhi + ((size_t)arow0 * T_TOT + t) * V_TOT + sw;
    const f16* Xh1 = Xhi + ((size_t)arow1 * T_TOT + t) * V_TOT + sw;
    const f16* Xl0 = Xlo + ((size_t)arow0 * T_TOT + t) * V_TOT + sw;
    const f16* Xl1 = Xlo + ((size_t)arow1 * T_TOT + t) * V_TOT + sw;
    const f16* Wih = Wihi + (size_t)(b * H_TOT + brow) * V_TOT + sw;
    const f16* Wil = Wilo + (size_t)(b * H_TOT + brow) * V_TOT + sw;

    // stage chunk k into buffer k&1 (k==16 -> input term X / W_in).
    // B first (possibly-L3 source: longest latency, issue earliest).
    auto STAGE = [&](int k) {
        const int bb = k & 1;
        if (k < 16) {
            const size_t off = (size_t)k * 64;
            GLOAD16(Bh0 + off, &Bs_hi[bb][dB]);
            GLOAD16(Bl0 + off, &Bs_lo[bb][dB]);
            GLOAD16(Ah0 + off, &As_hi[bb][dA0]);
            GLOAD16(Ah1 + off, &As_hi[bb][dA1]);
            GLOAD16(Al0 + off, &As_lo[bb][dA0]);
            GLOAD16(Al1 + off, &As_lo[bb][dA1]);
        } else {
            GLOAD16(Wih, &Bs_hi[bb][dB]);
            GLOAD16(Wil, &Bs_lo[bb][dB]);
            GLOAD16(Xh0, &As_hi[bb][dA0]);
            GLOAD16(Xh1, &As_hi[bb][dA1]);
            GLOAD16(Xl0, &As_lo[bb][dA0]);
            GLOAD16(Xl1, &As_lo[bb][dA1]);
        }
    };

    floatx4 acc[2], accl[2];
#pragma unroll
    for (int j = 0; j < 2; ++j) { acc[j] = (floatx4)(0.0f); accl[j] = (floatx4)(0.0f); }

    // swizzled ds_read addresses (f16 elems); chunk-invariant.
    const int xsw = (l16 & 7) << 3;
    const int aoff[2] = {
        (w * 16 + l16) * 64 + ((0 + oct * 8) ^ xsw),
        (w * 16 + l16) * 64 + ((32 + oct * 8) ^ xsw)
    };
    int boff[2][2];
#pragma unroll
    for (int nf = 0; nf < 2; ++nf) {
        boff[nf][0] = (nf * 16 + l16) * 64 + ((0 + oct * 8) ^ xsw);
        boff[nf][1] = (nf * 16 + l16) * 64 + ((32 + oct * 8) ^ xsw);
    }

    const int kc0 = first ? 16 : 0;
    STAGE(kc0);
    __syncthreads();   // vmcnt(0) drain: buffer kc0&1 ready

    for (int kc = kc0; kc <= 16; ++kc) {
        const int bb = kc & 1;
        if (kc < 16) STAGE(kc + 1);   // DMA next chunk into other buffer

#pragma unroll
        for (int half = 0; half < 2; ++half) {
            const f16x8 ah = *(const f16x8*)&As_hi[bb][aoff[half]];
            const f16x8 al = *(const f16x8*)&As_lo[bb][aoff[half]];
#pragma unroll
            for (int nf = 0; nf < 2; ++nf) {
                const f16x8 bh = *(const f16x8*)&Bs_hi[bb][boff[nf][half]];
                const f16x8 bl = *(const f16x8*)&Bs_lo[bb][boff[nf][half]];
                acc[nf]  = __builtin_amdgcn_mfma_f32_16x16x32_f16(ah, bh, acc[nf], 0, 0, 0);
                accl[nf] = __builtin_amdgcn_mfma_f32_16x16x32_f16(ah, bl, accl[nf], 0, 0, 0);
                accl[nf] = __builtin_amdgcn_mfma_f32_16x16x32_f16(al, bh, accl[nf], 0, 0, 0);
            }
        }
        if (kc < 16) __syncthreads();   // next buffer DMA'd; this buffer free
    }

    // ---- epilogue: tanh -> split-store state; head partial -> part[] ----
    // C/D map (16x16x32): col = lane&15, row = oct*4 + r.
    const int nbase = mt * 64;
    const int ibase = it * 32;

    const float* wl = W_lin + (size_t)t * C_TOT * F_TOT + b * H_TOT + ibase;
    float wv[4][2];
#pragma unroll
    for (int c = 0; c < 4; ++c)
#pragma unroll
        for (int nf = 0; nf < 2; ++nf)
            wv[c][nf] = wl[(size_t)c * F_TOT + nf * 16 + l16];

    float sval[2][4];
#pragma unroll
    for (int nf = 0; nf < 2; ++nf)
#pragma unroll
        for (int r = 0; r < 4; ++r) {
            const int m  = w * 16 + oct * 4 + r;    // batch row within tile
            const int ii = nf * 16 + l16;           // unit col within tile
            const float s = tanhf(acc[nf][r] + accl[nf][r] * LO_INV);
            sval[nf][r] = s;
            const f16 h = (f16)s;
            const size_t oidx = (size_t)(b * N_TOT + nbase + m) * H_TOT + ibase + ii;
            shi_n[oidx] = h;
            slo_n[oidx] = (f16)((s - (float)h) * LO_SCALE);
        }

    const int g = b * 32 + it;
#pragma unroll
    for (int r = 0; r < 4; ++r) {
        float v[4];
#pragma unroll
        for (int c = 0; c < 4; ++c) {
            float x = sval[0][r] * wv[c][0] + sval[1][r] * wv[c][1];
            x += __shfl_xor(x, 1);
            x += __shfl_xor(x, 2);
            x += __shfl_xor(x, 4);
            x += __shfl_xor(x, 8);
            v[c] = x;
        }
        if (l16 == 0) {
            const int n = nbase + w * 16 + oct * 4 + r;
            float4 o = {v[0], v[1], v[2], v[3]};
            *(float4*)&part[(((size_t)t * G_TOT + g) * N_TOT + n) * C_TOT] = o;
        }
    }
}

extern "C" void kernel_launch(void* const* d_in, const int* in_sizes, int n_in,
                              void* d_out, int out_size, void* d_ws, size_t ws_size,
                              hipStream_t stream) {
    const float* X     = (const float*)d_in[0]; // [256,70,64]
    const float* W_res = (const float*)d_in[1]; // [6,1024,1024]
    const float* W_in  = (const float*)d_in[2]; // [6,1024,64]
    const float* W_lin = (const float*)d_in[3]; // [70,4,6144]
    const float* b_lin = (const float*)d_in[4]; // [70,4]

    float* out    = (float*)d_out;
    float* logits = out;                                  // T*N*C fp32
    float* preds  = out + (size_t)T_TOT * N_TOT * C_TOT;  // T*N   fp32

    const size_t nWres = (size_t)B_TOT * H_TOT * H_TOT;   // 6,291,456
    const size_t nWin  = (size_t)B_TOT * H_TOT * V_TOT;   //   393,216
    const size_t nX    = (size_t)N_TOT * T_TOT * V_TOT;   // 1,146,880
    const size_t nS    = (size_t)B_TOT * N_TOT * H_TOT;   // 1,572,864

    f16* p    = (f16*)d_ws;                               // f16 arena ~43.9 MB
    f16* Whi  = p;  p += nWres;
    f16* Wlo  = p;  p += nWres;
    f16* Wihi = p;  p += nWin;
    f16* Wilo = p;  p += nWin;
    f16* Xhi  = p;  p += nX;
    f16* Xlo  = p;  p += nX;
    f16* sAh  = p;  p += nS;
    f16* sAl  = p;  p += nS;
    f16* sBh  = p;  p += nS;
    f16* sBl  = p;  p += nS;
    float* part = (float*)p;                              // +55 MB (ws ~268 MB)

    // one-time pre-splits (stream-ordered before the loop)
    split_f32<<<(int)(nWres / 2048), 256, 0, stream>>>(W_res, Whi, Wlo, (int)nWres);
    split_f32<<<(int)(nWin  / 2048), 256, 0, stream>>>(W_in, Wihi, Wilo, (int)nWin);
    split_f32<<<(int)(nX    / 2048), 256, 0, stream>>>(X, Xhi, Xlo, (int)nX);

    for (int t = 0; t < T_TOT; ++t) {
        const f16 *ph, *pl;
        f16 *nh, *nl;
        if (t & 1) { ph = sBh; pl = sBl; nh = sAh; nl = sAl; }
        else       { ph = sAh; pl = sAl; nh = sBh; nl = sBl; }
        esn_step_fused<<<B_TOT * 4 * 32, 256, 0, stream>>>(
            Xhi, Xlo, Whi, Wlo, Wihi, Wilo, ph, pl, nh, nl,
            W_lin, part, t, t == 0 ? 1 : 0);
    }
    head_reduce<<<T_TOT, 256, 0, stream>>>(part, b_lin, logits, preds);
}